// Round 1
// 4056.001 us; speedup vs baseline: 5.5184x; 5.5184x over previous
//
#include <hip/hip_runtime.h>
#include <stdint.h>

#define N_NODES 100000
#define N_EDGES 1600000
#define CH 128
#define EDGE_DIM 16
#define KMSG (CH + EDGE_DIM)  // 144
#define KUPD (2 * CH)         // 256
#define EPW 16                // edges per wave (msg)
#define NPW 8                 // nodes per wave (upd)

__device__ __forceinline__ float bf2f(ushort u) {
  union { uint i; float f; } c; c.i = ((uint)u) << 16; return c.f;
}
// dtype-dispatched scalar load (f32 or bf16 buffer)
__device__ __forceinline__ float ldf(const void* p, int f32, size_t i) {
  return f32 ? ((const float*)p)[i] : bf2f(((const ushort*)p)[i]);
}
// dtype-dispatched paired load: elements (2*pi, 2*pi+1)
__device__ __forceinline__ float2 ld2(const void* p, int f32, size_t pi) {
  if (f32) return ((const float2*)p)[pi];
  uint u = ((const uint*)p)[pi];
  return make_float2(bf2f((ushort)(u & 0xFFFF)), bf2f((ushort)(u >> 16)));
}
// x_sel: 0 = force bf16, 1 = use detected x flag, 2 = force f32
__device__ __forceinline__ int resolve_f32(int x_sel, const int* flags) {
  return (x_sel == 2) ? 1 : (x_sel == 1 ? flags[1] : 0);
}

// ---------------------------------------------------------------- runtime layout/dtype detection
// flags[0]=1 -> edge_index int32 [2,E]. flags[1..3]=1 -> x / edge_attr / weights are f32.
__global__ __launch_bounds__(256) void detect_kernel(const int* __restrict__ ei,
                                                     const ushort* __restrict__ xu,
                                                     const ushort* __restrict__ eau,
                                                     const ushort* __restrict__ wu,
                                                     int* __restrict__ flags) {
  int any = 0, fx = 0, fe = 0, fw = 0;
  for (int i = threadIdx.x; i < 4096; i += 256) any |= ei[2 * i + 1];
  for (int i = threadIdx.x; i < 16384; i += 256) {
    fx |= (((xu[2 * i] >> 7) & 0xFF) == 0xFF);
    fe |= (((eau[2 * i] >> 7) & 0xFF) == 0xFF);
  }
  for (int i = threadIdx.x; i < 8192; i += 256) {
    fw |= (((wu[2 * i] >> 7) & 0xFF) == 0xFF);
  }
  if (any) atomicOr(flags + 0, 1);
  if (fx)  atomicOr(flags + 1, 1);
  if (fe)  atomicOr(flags + 2, 1);
  if (fw)  atomicOr(flags + 3, 1);
}

__device__ __forceinline__ void load_edge(const int* __restrict__ ei, int i32, int e,
                                          int& s, int& d) {
  if (i32) { s = ei[e]; d = ei[N_EDGES + e]; }
  else     { s = ei[2 * e]; d = ei[2 * N_EDGES + 2 * e]; }
  s = min(max(s, 0), N_NODES - 1);
  d = min(max(d, 0), N_NODES - 1);
}

// ---------------------------------------------------------------- degree count
__global__ __launch_bounds__(256) void count_kernel(const int* __restrict__ ei,
                                                    const int* __restrict__ flags,
                                                    int* __restrict__ cnt) {
  int e = blockIdx.x * 256 + threadIdx.x;
  if (e >= N_EDGES) return;
  int s, d;
  load_edge(ei, flags[0], e, s, d);
  atomicAdd(&cnt[d], 1);
}

// ---------------------------------------------------------------- message, tiled:
// Each wave owns EPW=16 edges. Stage A-rows [x[src] || ea[e]] (f32) into a
// wave-private LDS slice, then one k-loop where each 512B W slice is reused by
// all 16 edges (W L1 traffic per edge drops 73.7KB -> 4.6KB, the R0 bottleneck).
// LDS reads are wave-uniform broadcasts (conflict-free). Math order over k is
// identical to msg_simple (f32 fmac ascending k), so numerics are unchanged.
__global__ __launch_bounds__(256) void msg_tiled(const void* __restrict__ x, int x_sel,
                                                 const void* __restrict__ ea,
                                                 const void* __restrict__ W,
                                                 const void* __restrict__ bmsg,
                                                 const int* __restrict__ ei,
                                                 const int* __restrict__ flags,
                                                 float* __restrict__ agg) {
  __shared__ float xs[4][EPW][KMSG];  // 36.9 KB -> 4 blocks/CU (16 waves/CU)
  const int wave = threadIdx.x >> 6;
  const int lane = threadIdx.x & 63;
  const int e0 = (blockIdx.x * 4 + wave) * EPW;  // grid sized exactly: E = 64 * gridDim
  const int xf = resolve_f32(x_sel, flags), ef = flags[2], wf = flags[3], i32 = flags[0];

  int dstv[EPW];
#pragma unroll
  for (int r = 0; r < EPW; ++r) {
    int s, d;
    load_edge(ei, i32, e0 + r, s, d);
    dstv[r] = d;
    float2 a = ld2(x, xf, (size_t)s * 64 + lane);     // coalesced row gather
    xs[wave][r][2 * lane]     = a.x;
    xs[wave][r][2 * lane + 1] = a.y;
    if (lane < 8) {
      float2 t = ld2(ea, ef, (size_t)(e0 + r) * 8 + lane);
      xs[wave][r][CH + 2 * lane]     = t.x;
      xs[wave][r][CH + 2 * lane + 1] = t.y;
    }
  }
  __syncthreads();

  float acc0[EPW], acc1[EPW];
#pragma unroll
  for (int r = 0; r < EPW; ++r) { acc0[r] = 0.f; acc1[r] = 0.f; }

#pragma unroll 4
  for (int k = 0; k < KMSG; k += 2) {
    float2 w0 = ld2(W, wf, (size_t)k * 64 + lane);
    float2 w1 = ld2(W, wf, (size_t)(k + 1) * 64 + lane);
#pragma unroll
    for (int r = 0; r < EPW; ++r) {
      float2 a = *(const float2*)&xs[wave][r][k];  // LDS broadcast, 8B
      acc0[r] += a.x * w0.x;
      acc1[r] += a.x * w0.y;
      acc0[r] += a.y * w1.x;
      acc1[r] += a.y * w1.y;
    }
  }

  float2 b = ld2(bmsg, wf, lane);
#pragma unroll
  for (int r = 0; r < EPW; ++r) {
    float o0 = fmaxf(acc0[r] + b.x, 0.f);
    float o1 = fmaxf(acc1[r] + b.y, 0.f);
    atomicAdd(&agg[(size_t)dstv[r] * CH + 2 * lane], o0);
    atomicAdd(&agg[(size_t)dstv[r] * CH + 2 * lane + 1], o1);
  }
}

// ---------------------------------------------------------------- update, tiled:
// Each wave owns NPW=8 nodes; stage [x[n] || agg[n]/max(cnt,1)] rows in LDS,
// reuse each W slice across 8 nodes. raw may alias agg: each wave stages its own
// agg rows (value dependency chain load->LDS->acc->store orders the store after
// the load), rows are wave-exclusive.
__global__ __launch_bounds__(256) void upd_tiled(const void* __restrict__ x, int x_sel,
                                                 const float* __restrict__ agg,
                                                 const int* __restrict__ cnt,
                                                 const void* __restrict__ W,
                                                 const void* __restrict__ bupd,
                                                 const int* __restrict__ flags,
                                                 float* __restrict__ raw) {
  __shared__ float xs[4][NPW][KUPD];  // 32 KB
  const int wave = threadIdx.x >> 6;
  const int lane = threadIdx.x & 63;
  const int n0 = (blockIdx.x * 4 + wave) * NPW;  // N = 32 * gridDim exactly
  const int xf = resolve_f32(x_sel, flags), wf = flags[3];

#pragma unroll
  for (int r = 0; r < NPW; ++r) {
    int n = n0 + r;
    float2 a = ld2(x, xf, (size_t)n * 64 + lane);
    xs[wave][r][2 * lane]     = a.x;
    xs[wave][r][2 * lane + 1] = a.y;
    int c = cnt[n];
    float inv = 1.f / (float)(c > 1 ? c : 1);
    xs[wave][r][CH + 2 * lane]     = agg[(size_t)n * CH + 2 * lane] * inv;
    xs[wave][r][CH + 2 * lane + 1] = agg[(size_t)n * CH + 2 * lane + 1] * inv;
  }
  __syncthreads();

  float acc0[NPW], acc1[NPW];
#pragma unroll
  for (int r = 0; r < NPW; ++r) { acc0[r] = 0.f; acc1[r] = 0.f; }

#pragma unroll 4
  for (int k = 0; k < KUPD; k += 2) {
    float2 w0 = ld2(W, wf, (size_t)k * 64 + lane);
    float2 w1 = ld2(W, wf, (size_t)(k + 1) * 64 + lane);
#pragma unroll
    for (int r = 0; r < NPW; ++r) {
      float2 a = *(const float2*)&xs[wave][r][k];
      acc0[r] += a.x * w0.x;
      acc1[r] += a.x * w0.y;
      acc0[r] += a.y * w1.x;
      acc1[r] += a.y * w1.y;
    }
  }

  float2 b = ld2(bupd, wf, lane);
#pragma unroll
  for (int r = 0; r < NPW; ++r) {
    size_t n = (size_t)(n0 + r);
    raw[n * CH + 2 * lane]     = acc0[r] + b.x;
    raw[n * CH + 2 * lane + 1] = acc1[r] + b.y;
  }
}

// ---------------------------------------------------------------- row L2-normalize + bias (+optional ReLU) -> f32
__global__ __launch_bounds__(256) void norm_simple(const float* __restrict__ raw,
                                                   const void* __restrict__ bias,
                                                   const int* __restrict__ flags,
                                                   float* __restrict__ out,
                                                   int relu) {
  int row = blockIdx.x * 4 + (threadIdx.x >> 6);
  int lane = threadIdx.x & 63;
  const int wf = flags[3];
  float v0 = raw[(size_t)row * CH + 2 * lane];
  float v1 = raw[(size_t)row * CH + 2 * lane + 1];
  float ss = v0 * v0 + v1 * v1;
#pragma unroll
  for (int o = 32; o; o >>= 1) ss += __shfl_xor(ss, o);
  float inv = 1.0f / fmaxf(sqrtf(ss), 1e-12f);
  float2 b = ld2(bias, wf, lane);
  float o0 = v0 * inv + b.x;
  float o1 = v1 * inv + b.y;
  if (relu) {
    o0 = fmaxf(o0, 0.0f);
    o1 = fmaxf(o1, 0.0f);
  }
  out[(size_t)row * CH + 2 * lane] = o0;
  out[(size_t)row * CH + 2 * lane + 1] = o1;
}

// ---------------------------------------------------------------- host
extern "C" void kernel_launch(void* const* d_in, const int* in_sizes, int n_in,
                              void* d_out, int out_size, void* d_ws, size_t ws_size,
                              hipStream_t stream) {
  const void* x   = d_in[0];
  const int*  ei  = (const int*)d_in[1];
  const void* ea  = d_in[2];
  const void* wm1 = d_in[3];
  const void* bm1 = d_in[4];
  const void* wu1 = d_in[5];
  const void* bu1 = d_in[6];
  const void* bi1 = d_in[7];
  const void* wm2 = d_in[8];
  const void* bm2 = d_in[9];
  const void* wu2 = d_in[10];
  const void* bu2 = d_in[11];
  const void* bi2 = d_in[12];
  float* out = (float*)d_out;

  // Workspace (51.6 MB): flags | cnt | agg (raw aliased).
  // Layer-1 h (f32) lives in d_out: norm1 writes it, layer 2 consumes it
  // (x_sel=2 force-f32), norm2 overwrites d_out with the final output.
  char* base = (char*)d_ws;
  size_t off = 0;
  auto alloc = [&](size_t b) { size_t o = off; off += (b + 255) & ~(size_t)255; return o; };
  size_t flags_o = alloc(16);
  size_t cnt_o   = alloc((size_t)N_NODES * 4);
  size_t agg_o   = alloc((size_t)N_NODES * CH * 4);
  size_t zero_end = off;
  (void)ws_size; (void)n_in; (void)in_sizes; (void)out_size;

  int*   flags = (int*)(base + flags_o);
  int*   cntp  = (int*)(base + cnt_o);
  float* aggp  = (float*)(base + agg_o);
  float* rawp  = aggp;   // alias (see upd_tiled note)
  float* hp    = out;    // layer-1 output (f32) lives in d_out

  hipMemsetAsync(base, 0, zero_end, stream);
  detect_kernel<<<1, 256, 0, stream>>>(ei, (const ushort*)x, (const ushort*)ea,
                                       (const ushort*)wm1, flags);
  count_kernel<<<(N_EDGES + 255) / 256, 256, 0, stream>>>(ei, flags, cntp);

  const int mgrid = N_EDGES / (4 * EPW);   // 16 edges/wave, 4 waves/block = 25000
  const int ugrid = N_NODES / (4 * NPW);   // 8 nodes/wave, 4 waves/block  = 3125

  // ---- layer 1
  msg_tiled<<<mgrid, 256, 0, stream>>>(x, 1, ea, wm1, bm1, ei, flags, aggp);
  upd_tiled<<<ugrid, 256, 0, stream>>>(x, 1, aggp, cntp, wu1, bu1, flags, rawp);
  norm_simple<<<N_NODES / 4, 256, 0, stream>>>(rawp, bi1, flags, hp, 1);

  // ---- layer 2 (h is f32 in d_out -> x_sel=2 forces f32)
  hipMemsetAsync(base + agg_o, 0, (size_t)N_NODES * CH * 4, stream);
  msg_tiled<<<mgrid, 256, 0, stream>>>(hp, 2, ea, wm2, bm2, ei, flags, aggp);
  upd_tiled<<<ugrid, 256, 0, stream>>>(hp, 2, aggp, cntp, wu2, bu2, flags, rawp);
  norm_simple<<<N_NODES / 4, 256, 0, stream>>>(rawp, bi2, flags, out, 0);
}

// Round 2
// 2031.058 us; speedup vs baseline: 11.0202x; 1.9970x over previous
//
#include <hip/hip_runtime.h>
#include <stdint.h>

#define N_NODES 100000
#define N_EDGES 1600000
#define CH 128
#define EDGE_DIM 16
#define KUPD (2 * CH)         // 256
#define NPW 8                 // nodes per wave (gemm/upd)

__device__ __forceinline__ float bf2f(ushort u) {
  union { uint i; float f; } c; c.i = ((uint)u) << 16; return c.f;
}
// dtype-dispatched scalar load (f32 or bf16 buffer)
__device__ __forceinline__ float ldf(const void* p, int f32, size_t i) {
  return f32 ? ((const float*)p)[i] : bf2f(((const ushort*)p)[i]);
}
// dtype-dispatched paired load: elements (2*pi, 2*pi+1)
__device__ __forceinline__ float2 ld2(const void* p, int f32, size_t pi) {
  if (f32) return ((const float2*)p)[pi];
  uint u = ((const uint*)p)[pi];
  return make_float2(bf2f((ushort)(u & 0xFFFF)), bf2f((ushort)(u >> 16)));
}
// x_sel: 0 = force bf16, 1 = use detected x flag, 2 = force f32
__device__ __forceinline__ int resolve_f32(int x_sel, const int* flags) {
  return (x_sel == 2) ? 1 : (x_sel == 1 ? flags[1] : 0);
}

// ---------------------------------------------------------------- runtime layout/dtype detection
// flags[0]=1 -> edge_index int32 [2,E]. flags[1..3]=1 -> x / edge_attr / weights are f32.
__global__ __launch_bounds__(256) void detect_kernel(const int* __restrict__ ei,
                                                     const ushort* __restrict__ xu,
                                                     const ushort* __restrict__ eau,
                                                     const ushort* __restrict__ wu,
                                                     int* __restrict__ flags) {
  int any = 0, fx = 0, fe = 0, fw = 0;
  for (int i = threadIdx.x; i < 4096; i += 256) any |= ei[2 * i + 1];
  for (int i = threadIdx.x; i < 16384; i += 256) {
    fx |= (((xu[2 * i] >> 7) & 0xFF) == 0xFF);
    fe |= (((eau[2 * i] >> 7) & 0xFF) == 0xFF);
  }
  for (int i = threadIdx.x; i < 8192; i += 256) {
    fw |= (((wu[2 * i] >> 7) & 0xFF) == 0xFF);
  }
  if (any) atomicOr(flags + 0, 1);
  if (fx)  atomicOr(flags + 1, 1);
  if (fe)  atomicOr(flags + 2, 1);
  if (fw)  atomicOr(flags + 3, 1);
}

__device__ __forceinline__ void load_edge(const int* __restrict__ ei, int i32, int e,
                                          int& s, int& d) {
  if (i32) { s = ei[e]; d = ei[N_EDGES + e]; }
  else     { s = ei[2 * e]; d = ei[2 * N_EDGES + 2 * e]; }
  s = min(max(s, 0), N_NODES - 1);
  d = min(max(d, 0), N_NODES - 1);
}

// ---------------------------------------------------------------- degree count
__global__ __launch_bounds__(256) void count_kernel(const int* __restrict__ ei,
                                                    const int* __restrict__ flags,
                                                    int* __restrict__ cnt) {
  int e = blockIdx.x * 256 + threadIdx.x;
  if (e >= N_EDGES) return;
  int s, d;
  load_edge(ei, flags[0], e, s, d);
  atomicAdd(&cnt[d], 1);
}

// ---------------------------------------------------------------- exclusive prefix scan of cnt -> rowptr
// One block, 1024 threads, each owns a 98-element chunk; Hillis-Steele over partials.
__global__ __launch_bounds__(1024) void scan_kernel(const int* __restrict__ cnt,
                                                    int* __restrict__ rowptr) {
  __shared__ int part[1024];
  const int t = threadIdx.x;
  const int CHUNK = (N_NODES + 1023) / 1024;  // 98
  int base = t * CHUNK;
  int lim = min(base + CHUNK, N_NODES);
  int s = 0;
  for (int i = base; i < lim; ++i) s += cnt[i];
  part[t] = s;
  __syncthreads();
  for (int off = 1; off < 1024; off <<= 1) {
    int v = (t >= off) ? part[t - off] : 0;
    __syncthreads();
    part[t] += v;
    __syncthreads();
  }
  int excl = (t == 0) ? 0 : part[t - 1];
  for (int i = base; i < lim; ++i) { rowptr[i] = excl; excl += cnt[i]; }
  if (t == 1023) rowptr[N_NODES] = part[1023];
}

// ---------------------------------------------------------------- CSR scatter: eid sorted by dst
__global__ __launch_bounds__(256) void scatter_kernel(const int* __restrict__ ei,
                                                      const int* __restrict__ flags,
                                                      const int* __restrict__ rowptr,
                                                      int* __restrict__ fill,
                                                      int* __restrict__ eidv) {
  int e = blockIdx.x * 256 + threadIdx.x;
  if (e >= N_EDGES) return;
  int s, d;
  load_edge(ei, flags[0], e, s, d);
  int pos = atomicAdd(&fill[d], 1);
  eidv[rowptr[d] + pos] = e;
}

// ---------------------------------------------------------------- node-level GEMM: y = x @ W[0:128] + b
// The x-part of the message Linear is per-SOURCE-NODE, not per-edge: computing it
// once here cuts msg FLOPs 6x (59 -> 10 GFLOP). Same tiling as upd_tiled.
__global__ __launch_bounds__(256) void gemm_node(const void* __restrict__ x, int x_sel,
                                                 const void* __restrict__ W,
                                                 const void* __restrict__ b,
                                                 const int* __restrict__ flags,
                                                 float* __restrict__ y) {
  __shared__ float xs[4][NPW][CH];  // 16 KB
  const int wave = threadIdx.x >> 6;
  const int lane = threadIdx.x & 63;
  const int n0 = (blockIdx.x * 4 + wave) * NPW;  // N = 32*gridDim exactly
  const int xf = resolve_f32(x_sel, flags), wf = flags[3];

#pragma unroll
  for (int r = 0; r < NPW; ++r) {
    float2 a = ld2(x, xf, (size_t)(n0 + r) * 64 + lane);
    xs[wave][r][2 * lane]     = a.x;
    xs[wave][r][2 * lane + 1] = a.y;
  }
  __syncthreads();

  float acc0[NPW], acc1[NPW];
#pragma unroll
  for (int r = 0; r < NPW; ++r) { acc0[r] = 0.f; acc1[r] = 0.f; }

#pragma unroll 4
  for (int k = 0; k < CH; k += 2) {
    float2 w0 = ld2(W, wf, (size_t)k * 64 + lane);
    float2 w1 = ld2(W, wf, (size_t)(k + 1) * 64 + lane);
#pragma unroll
    for (int r = 0; r < NPW; ++r) {
      float2 a = *(const float2*)&xs[wave][r][k];
      acc0[r] += a.x * w0.x;
      acc1[r] += a.x * w0.y;
      acc0[r] += a.y * w1.x;
      acc1[r] += a.y * w1.y;
    }
  }

  float2 bb = ld2(b, wf, lane);
#pragma unroll
  for (int r = 0; r < NPW; ++r) {
    size_t n = (size_t)(n0 + r);
    y[n * CH + 2 * lane]     = acc0[r] + bb.x;
    y[n * CH + 2 * lane + 1] = acc1[r] + bb.y;
  }
}

// ---------------------------------------------------------------- CSR aggregation (atomic-free):
// One wave per dst node. For each incoming edge: gather y[src] (L3-resident),
// add the ea@W_e part (K=16, W_e staged in LDS), ReLU, accumulate in registers.
// Each agg row is written exactly once -> no atomics, write traffic 1.6GB -> 51MB.
__global__ __launch_bounds__(256) void agg_csr(const float2* __restrict__ y,
                                               const void* __restrict__ ea,
                                               const void* __restrict__ W,
                                               const int* __restrict__ rowptr,
                                               const int* __restrict__ eidv,
                                               const int* __restrict__ ei,
                                               const int* __restrict__ flags,
                                               float* __restrict__ agg) {
  __shared__ float we[EDGE_DIM][CH];  // 8 KB: W rows 128..143
  const int wave = threadIdx.x >> 6;
  const int lane = threadIdx.x & 63;
  const int ef = flags[2], wf = flags[3], i32 = flags[0];

  for (int i = threadIdx.x; i < EDGE_DIM * 64; i += 256) {
    float2 wv = ld2(W, wf, (size_t)(CH + (i >> 6)) * 64 + (i & 63));
    we[i >> 6][2 * (i & 63)]     = wv.x;
    we[i >> 6][2 * (i & 63) + 1] = wv.y;
  }
  __syncthreads();

  const int n = blockIdx.x * 4 + wave;  // grid = N/4 exactly
  const int beg = rowptr[n], end = rowptr[n + 1];
  float acc0 = 0.f, acc1 = 0.f;

  // 2-stage pipeline: prefetch next (e, src) while computing current edge.
  int e = 0, s = 0;
  if (beg < end) {
    e = eidv[beg];
    s = i32 ? ei[e] : ei[2 * e];
    s = min(max(s, 0), N_NODES - 1);
  }
  for (int j = beg; j < end; ++j) {
    const int ec = e;
    float2 yv = y[(size_t)s * 64 + lane];  // issue gather early
    if (j + 1 < end) {
      e = eidv[j + 1];
      s = i32 ? ei[e] : ei[2 * e];
      s = min(max(s, 0), N_NODES - 1);
    }
    float z0 = 0.f, z1 = 0.f;
#pragma unroll
    for (int k = 0; k < EDGE_DIM; k += 2) {
      float2 t = ld2(ea, ef, (size_t)ec * 8 + (k >> 1));  // wave-uniform
      z0 += t.x * we[k][2 * lane];
      z1 += t.x * we[k][2 * lane + 1];
      z0 += t.y * we[k + 1][2 * lane];
      z1 += t.y * we[k + 1][2 * lane + 1];
    }
    acc0 += fmaxf(yv.x + z0, 0.f);
    acc1 += fmaxf(yv.y + z1, 0.f);
  }
  agg[(size_t)n * CH + 2 * lane]     = acc0;
  agg[(size_t)n * CH + 2 * lane + 1] = acc1;
}

// ---------------------------------------------------------------- update, tiled (unchanged from R1):
// raw may alias agg: each wave stages its own agg rows before storing, rows wave-exclusive.
__global__ __launch_bounds__(256) void upd_tiled(const void* __restrict__ x, int x_sel,
                                                 const float* __restrict__ agg,
                                                 const int* __restrict__ cnt,
                                                 const void* __restrict__ W,
                                                 const void* __restrict__ bupd,
                                                 const int* __restrict__ flags,
                                                 float* __restrict__ raw) {
  __shared__ float xs[4][NPW][KUPD];  // 32 KB
  const int wave = threadIdx.x >> 6;
  const int lane = threadIdx.x & 63;
  const int n0 = (blockIdx.x * 4 + wave) * NPW;
  const int xf = resolve_f32(x_sel, flags), wf = flags[3];

#pragma unroll
  for (int r = 0; r < NPW; ++r) {
    int n = n0 + r;
    float2 a = ld2(x, xf, (size_t)n * 64 + lane);
    xs[wave][r][2 * lane]     = a.x;
    xs[wave][r][2 * lane + 1] = a.y;
    int c = cnt[n];
    float inv = 1.f / (float)(c > 1 ? c : 1);
    xs[wave][r][CH + 2 * lane]     = agg[(size_t)n * CH + 2 * lane] * inv;
    xs[wave][r][CH + 2 * lane + 1] = agg[(size_t)n * CH + 2 * lane + 1] * inv;
  }
  __syncthreads();

  float acc0[NPW], acc1[NPW];
#pragma unroll
  for (int r = 0; r < NPW; ++r) { acc0[r] = 0.f; acc1[r] = 0.f; }

#pragma unroll 4
  for (int k = 0; k < KUPD; k += 2) {
    float2 w0 = ld2(W, wf, (size_t)k * 64 + lane);
    float2 w1 = ld2(W, wf, (size_t)(k + 1) * 64 + lane);
#pragma unroll
    for (int r = 0; r < NPW; ++r) {
      float2 a = *(const float2*)&xs[wave][r][k];
      acc0[r] += a.x * w0.x;
      acc1[r] += a.x * w0.y;
      acc0[r] += a.y * w1.x;
      acc1[r] += a.y * w1.y;
    }
  }

  float2 b = ld2(bupd, wf, lane);
#pragma unroll
  for (int r = 0; r < NPW; ++r) {
    size_t n = (size_t)(n0 + r);
    raw[n * CH + 2 * lane]     = acc0[r] + b.x;
    raw[n * CH + 2 * lane + 1] = acc1[r] + b.y;
  }
}

// ---------------------------------------------------------------- row L2-normalize + bias (+optional ReLU) -> f32
__global__ __launch_bounds__(256) void norm_simple(const float* __restrict__ raw,
                                                   const void* __restrict__ bias,
                                                   const int* __restrict__ flags,
                                                   float* __restrict__ out,
                                                   int relu) {
  int row = blockIdx.x * 4 + (threadIdx.x >> 6);
  int lane = threadIdx.x & 63;
  const int wf = flags[3];
  float v0 = raw[(size_t)row * CH + 2 * lane];
  float v1 = raw[(size_t)row * CH + 2 * lane + 1];
  float ss = v0 * v0 + v1 * v1;
#pragma unroll
  for (int o = 32; o; o >>= 1) ss += __shfl_xor(ss, o);
  float inv = 1.0f / fmaxf(sqrtf(ss), 1e-12f);
  float2 b = ld2(bias, wf, lane);
  float o0 = v0 * inv + b.x;
  float o1 = v1 * inv + b.y;
  if (relu) {
    o0 = fmaxf(o0, 0.0f);
    o1 = fmaxf(o1, 0.0f);
  }
  out[(size_t)row * CH + 2 * lane] = o0;
  out[(size_t)row * CH + 2 * lane + 1] = o1;
}

// ---------------------------------------------------------------- host
extern "C" void kernel_launch(void* const* d_in, const int* in_sizes, int n_in,
                              void* d_out, int out_size, void* d_ws, size_t ws_size,
                              hipStream_t stream) {
  const void* x   = d_in[0];
  const int*  ei  = (const int*)d_in[1];
  const void* ea  = d_in[2];
  const void* wm1 = d_in[3];
  const void* bm1 = d_in[4];
  const void* wu1 = d_in[5];
  const void* bu1 = d_in[6];
  const void* bi1 = d_in[7];
  const void* wm2 = d_in[8];
  const void* bm2 = d_in[9];
  const void* wu2 = d_in[10];
  const void* bu2 = d_in[11];
  const void* bi2 = d_in[12];
  float* out = (float*)d_out;

  // Workspace (~110 MB): flags | cnt | fill | rowptr | eid (CSR) | A=agg/raw | B=y.
  // h (layer-1 output, f32) lives in d_out between norm1 and norm2, as before.
  char* base = (char*)d_ws;
  size_t off = 0;
  auto alloc = [&](size_t b) { size_t o = off; off += (b + 255) & ~(size_t)255; return o; };
  size_t flags_o = alloc(16);
  size_t cnt_o   = alloc((size_t)N_NODES * 4);
  size_t fill_o  = alloc((size_t)N_NODES * 4);
  size_t zero_end = off;                       // memset covers flags|cnt|fill only
  size_t rowp_o  = alloc((size_t)(N_NODES + 1) * 4);
  size_t eid_o   = alloc((size_t)N_EDGES * 4);
  size_t agg_o   = alloc((size_t)N_NODES * CH * 4);
  size_t y_o     = alloc((size_t)N_NODES * CH * 4);
  (void)ws_size; (void)n_in; (void)in_sizes; (void)out_size;

  int*    flags = (int*)(base + flags_o);
  int*    cntp  = (int*)(base + cnt_o);
  int*    fillp = (int*)(base + fill_o);
  int*    rowp  = (int*)(base + rowp_o);
  int*    eidp  = (int*)(base + eid_o);
  float*  aggp  = (float*)(base + agg_o);
  float*  rawp  = aggp;                 // alias (see upd_tiled note)
  float2* yp    = (float2*)(base + y_o);
  float*  hp    = out;                  // layer-1 output (f32) lives in d_out

  hipMemsetAsync(base, 0, zero_end, stream);
  detect_kernel<<<1, 256, 0, stream>>>(ei, (const ushort*)x, (const ushort*)ea,
                                       (const ushort*)wm1, flags);
  count_kernel<<<(N_EDGES + 255) / 256, 256, 0, stream>>>(ei, flags, cntp);
  scan_kernel<<<1, 1024, 0, stream>>>(cntp, rowp);
  scatter_kernel<<<(N_EDGES + 255) / 256, 256, 0, stream>>>(ei, flags, rowp, fillp, eidp);

  const int ggrid = N_NODES / (4 * NPW);  // 3125
  const int agrid = N_NODES / 4;          // 25000 (one wave per node)

  // ---- layer 1
  gemm_node<<<ggrid, 256, 0, stream>>>(x, 1, wm1, bm1, flags, (float*)yp);
  agg_csr<<<agrid, 256, 0, stream>>>(yp, ea, wm1, rowp, eidp, ei, flags, aggp);
  upd_tiled<<<ggrid, 256, 0, stream>>>(x, 1, aggp, cntp, wu1, bu1, flags, rawp);
  norm_simple<<<N_NODES / 4, 256, 0, stream>>>(rawp, bi1, flags, hp, 1);

  // ---- layer 2 (h is f32 in d_out -> x_sel=2 forces f32)
  gemm_node<<<ggrid, 256, 0, stream>>>(hp, 2, wm2, bm2, flags, (float*)yp);
  agg_csr<<<agrid, 256, 0, stream>>>(yp, ea, wm2, rowp, eidp, ei, flags, aggp);
  upd_tiled<<<ggrid, 256, 0, stream>>>(hp, 2, aggp, cntp, wu2, bu2, flags, rawp);
  norm_simple<<<N_NODES / 4, 256, 0, stream>>>(rawp, bi2, flags, out, 0);
}

// Round 3
// 1822.912 us; speedup vs baseline: 12.2785x; 1.1142x over previous
//
#include <hip/hip_runtime.h>
#include <stdint.h>

#define N_NODES 100000
#define N_EDGES 1600000
#define CH 128
#define EDGE_DIM 16
#define KUPD (2 * CH)         // 256
#define NPW 8                 // nodes per wave (gemm/upd)

__device__ __forceinline__ float bf2f(ushort u) {
  union { uint i; float f; } c; c.i = ((uint)u) << 16; return c.f;
}
// dtype-dispatched scalar load (f32 or bf16 buffer)
__device__ __forceinline__ float ldf(const void* p, int f32, size_t i) {
  return f32 ? ((const float*)p)[i] : bf2f(((const ushort*)p)[i]);
}
// dtype-dispatched paired load: elements (2*pi, 2*pi+1)
__device__ __forceinline__ float2 ld2(const void* p, int f32, size_t pi) {
  if (f32) return ((const float2*)p)[pi];
  uint u = ((const uint*)p)[pi];
  return make_float2(bf2f((ushort)(u & 0xFFFF)), bf2f((ushort)(u >> 16)));
}
// dtype-dispatched quad load: elements (4*qi .. 4*qi+3)
__device__ __forceinline__ float4 ld4(const void* p, int f32, size_t qi) {
  if (f32) return ((const float4*)p)[qi];
  uint2 u = ((const uint2*)p)[qi];
  float4 r;
  r.x = bf2f((ushort)(u.x & 0xFFFF)); r.y = bf2f((ushort)(u.x >> 16));
  r.z = bf2f((ushort)(u.y & 0xFFFF)); r.w = bf2f((ushort)(u.y >> 16));
  return r;
}
// x_sel: 0 = force bf16, 1 = use detected x flag, 2 = force f32
__device__ __forceinline__ int resolve_f32(int x_sel, const int* flags) {
  return (x_sel == 2) ? 1 : (x_sel == 1 ? flags[1] : 0);
}

// ---------------------------------------------------------------- runtime layout/dtype detection
// flags[0]=1 -> edge_index int32 [2,E]. flags[1..3]=1 -> x / edge_attr / weights are f32.
__global__ __launch_bounds__(256) void detect_kernel(const int* __restrict__ ei,
                                                     const ushort* __restrict__ xu,
                                                     const ushort* __restrict__ eau,
                                                     const ushort* __restrict__ wu,
                                                     int* __restrict__ flags) {
  int any = 0, fx = 0, fe = 0, fw = 0;
  for (int i = threadIdx.x; i < 4096; i += 256) any |= ei[2 * i + 1];
  for (int i = threadIdx.x; i < 16384; i += 256) {
    fx |= (((xu[2 * i] >> 7) & 0xFF) == 0xFF);
    fe |= (((eau[2 * i] >> 7) & 0xFF) == 0xFF);
  }
  for (int i = threadIdx.x; i < 8192; i += 256) {
    fw |= (((wu[2 * i] >> 7) & 0xFF) == 0xFF);
  }
  if (any) atomicOr(flags + 0, 1);
  if (fx)  atomicOr(flags + 1, 1);
  if (fe)  atomicOr(flags + 2, 1);
  if (fw)  atomicOr(flags + 3, 1);
}

__device__ __forceinline__ void load_edge(const int* __restrict__ ei, int i32, int e,
                                          int& s, int& d) {
  if (i32) { s = ei[e]; d = ei[N_EDGES + e]; }
  else     { s = ei[2 * e]; d = ei[2 * N_EDGES + 2 * e]; }
  s = min(max(s, 0), N_NODES - 1);
  d = min(max(d, 0), N_NODES - 1);
}

// ---------------------------------------------------------------- degree count
__global__ __launch_bounds__(256) void count_kernel(const int* __restrict__ ei,
                                                    const int* __restrict__ flags,
                                                    int* __restrict__ cnt) {
  int e = blockIdx.x * 256 + threadIdx.x;
  if (e >= N_EDGES) return;
  int s, d;
  load_edge(ei, flags[0], e, s, d);
  atomicAdd(&cnt[d], 1);
}

// ---------------------------------------------------------------- exclusive prefix scan of cnt -> rowptr
__global__ __launch_bounds__(1024) void scan_kernel(const int* __restrict__ cnt,
                                                    int* __restrict__ rowptr) {
  __shared__ int part[1024];
  const int t = threadIdx.x;
  const int CHUNK = (N_NODES + 1023) / 1024;  // 98
  int base = t * CHUNK;
  int lim = min(base + CHUNK, N_NODES);
  int s = 0;
  for (int i = base; i < lim; ++i) s += cnt[i];
  part[t] = s;
  __syncthreads();
  for (int off = 1; off < 1024; off <<= 1) {
    int v = (t >= off) ? part[t - off] : 0;
    __syncthreads();
    part[t] += v;
    __syncthreads();
  }
  int excl = (t == 0) ? 0 : part[t - 1];
  for (int i = base; i < lim; ++i) { rowptr[i] = excl; excl += cnt[i]; }
  if (t == 1023) rowptr[N_NODES] = part[1023];
}

// ---------------------------------------------------------------- CSR scatter: {src, eid} sorted by dst
// Storing src alongside eid removes the dependent eid->edge_index load chain
// from the hot agg kernel (R2's latency limiter).
__global__ __launch_bounds__(256) void scatter_kernel(const int* __restrict__ ei,
                                                      const int* __restrict__ flags,
                                                      const int* __restrict__ rowptr,
                                                      int* __restrict__ fill,
                                                      int2* __restrict__ sev) {
  int e = blockIdx.x * 256 + threadIdx.x;
  if (e >= N_EDGES) return;
  int s, d;
  load_edge(ei, flags[0], e, s, d);
  int pos = atomicAdd(&fill[d], 1);
  sev[rowptr[d] + pos] = make_int2(s, e);
}

// ---------------------------------------------------------------- node-level GEMM: y = x @ W[0:128] + b
__global__ __launch_bounds__(256) void gemm_node(const void* __restrict__ x, int x_sel,
                                                 const void* __restrict__ W,
                                                 const void* __restrict__ b,
                                                 const int* __restrict__ flags,
                                                 float* __restrict__ y) {
  __shared__ float xs[4][NPW][CH];  // 16 KB
  const int wave = threadIdx.x >> 6;
  const int lane = threadIdx.x & 63;
  const int n0 = (blockIdx.x * 4 + wave) * NPW;  // N = 32*gridDim exactly
  const int xf = resolve_f32(x_sel, flags), wf = flags[3];

#pragma unroll
  for (int r = 0; r < NPW; ++r) {
    float2 a = ld2(x, xf, (size_t)(n0 + r) * 64 + lane);
    xs[wave][r][2 * lane]     = a.x;
    xs[wave][r][2 * lane + 1] = a.y;
  }
  __syncthreads();

  float acc0[NPW], acc1[NPW];
#pragma unroll
  for (int r = 0; r < NPW; ++r) { acc0[r] = 0.f; acc1[r] = 0.f; }

#pragma unroll 4
  for (int k = 0; k < CH; k += 2) {
    float2 w0 = ld2(W, wf, (size_t)k * 64 + lane);
    float2 w1 = ld2(W, wf, (size_t)(k + 1) * 64 + lane);
#pragma unroll
    for (int r = 0; r < NPW; ++r) {
      float2 a = *(const float2*)&xs[wave][r][k];
      acc0[r] += a.x * w0.x;
      acc1[r] += a.x * w0.y;
      acc0[r] += a.y * w1.x;
      acc1[r] += a.y * w1.y;
    }
  }

  float2 bb = ld2(b, wf, lane);
#pragma unroll
  for (int r = 0; r < NPW; ++r) {
    size_t n = (size_t)(n0 + r);
    y[n * CH + 2 * lane]     = acc0[r] + bb.x;
    y[n * CH + 2 * lane + 1] = acc1[r] + bb.y;
  }
}

// ---------------------------------------------------------------- CSR aggregation, 4-edge batched:
// One wave per dst node. W_e slice (rows 128..143, this lane's 2 cols) lives in
// 32 VGPRs. Per iteration: 4 sequential sev loads, then ALL gathers for 4 edges
// issue before any use (4 y rows + 16 ea quads in flight -> 4x the R2 latency
// hiding). Math per edge identical to R2 (ascending-k fmac, CSR edge order).
__global__ __launch_bounds__(256, 4) void agg_csr(const float2* __restrict__ y,
                                                  const void* __restrict__ ea,
                                                  const void* __restrict__ W,
                                                  const int* __restrict__ rowptr,
                                                  const int2* __restrict__ sev,
                                                  const int* __restrict__ flags,
                                                  float* __restrict__ agg) {
  const int wave = threadIdx.x >> 6;
  const int lane = threadIdx.x & 63;
  const int ef = flags[2], wf = flags[3];

  float wex[EDGE_DIM], wey[EDGE_DIM];
#pragma unroll
  for (int k = 0; k < EDGE_DIM; ++k) {
    float2 wv = ld2(W, wf, (size_t)(CH + k) * 64 + lane);
    wex[k] = wv.x; wey[k] = wv.y;
  }

  const int n = blockIdx.x * 4 + wave;  // grid = N/4 exactly
  const int beg = rowptr[n], end = rowptr[n + 1];
  float acc0 = 0.f, acc1 = 0.f;

  auto edge = [&](float2 yv, float4 q0, float4 q1, float4 q2, float4 q3) {
    float av[16] = {q0.x, q0.y, q0.z, q0.w, q1.x, q1.y, q1.z, q1.w,
                    q2.x, q2.y, q2.z, q2.w, q3.x, q3.y, q3.z, q3.w};
    float z0 = 0.f, z1 = 0.f;
#pragma unroll
    for (int k = 0; k < EDGE_DIM; ++k) {
      z0 += av[k] * wex[k];
      z1 += av[k] * wey[k];
    }
    acc0 += fmaxf(yv.x + z0, 0.f);
    acc1 += fmaxf(yv.y + z1, 0.f);
  };

  int j = beg;
  for (; j + 4 <= end; j += 4) {
    int2 p0 = sev[j], p1 = sev[j + 1], p2 = sev[j + 2], p3 = sev[j + 3];
    float2 y0 = y[(size_t)p0.x * 64 + lane];
    float2 y1 = y[(size_t)p1.x * 64 + lane];
    float2 y2 = y[(size_t)p2.x * 64 + lane];
    float2 y3 = y[(size_t)p3.x * 64 + lane];
    float4 a00 = ld4(ea, ef, (size_t)p0.y * 4 + 0);
    float4 a01 = ld4(ea, ef, (size_t)p0.y * 4 + 1);
    float4 a02 = ld4(ea, ef, (size_t)p0.y * 4 + 2);
    float4 a03 = ld4(ea, ef, (size_t)p0.y * 4 + 3);
    float4 a10 = ld4(ea, ef, (size_t)p1.y * 4 + 0);
    float4 a11 = ld4(ea, ef, (size_t)p1.y * 4 + 1);
    float4 a12 = ld4(ea, ef, (size_t)p1.y * 4 + 2);
    float4 a13 = ld4(ea, ef, (size_t)p1.y * 4 + 3);
    float4 a20 = ld4(ea, ef, (size_t)p2.y * 4 + 0);
    float4 a21 = ld4(ea, ef, (size_t)p2.y * 4 + 1);
    float4 a22 = ld4(ea, ef, (size_t)p2.y * 4 + 2);
    float4 a23 = ld4(ea, ef, (size_t)p2.y * 4 + 3);
    float4 a30 = ld4(ea, ef, (size_t)p3.y * 4 + 0);
    float4 a31 = ld4(ea, ef, (size_t)p3.y * 4 + 1);
    float4 a32 = ld4(ea, ef, (size_t)p3.y * 4 + 2);
    float4 a33 = ld4(ea, ef, (size_t)p3.y * 4 + 3);
    edge(y0, a00, a01, a02, a03);
    edge(y1, a10, a11, a12, a13);
    edge(y2, a20, a21, a22, a23);
    edge(y3, a30, a31, a32, a33);
  }
  for (; j < end; ++j) {  // tail (wave-uniform trip count)
    int2 p = sev[j];
    float2 yv = y[(size_t)p.x * 64 + lane];
    float4 q0 = ld4(ea, ef, (size_t)p.y * 4 + 0);
    float4 q1 = ld4(ea, ef, (size_t)p.y * 4 + 1);
    float4 q2 = ld4(ea, ef, (size_t)p.y * 4 + 2);
    float4 q3 = ld4(ea, ef, (size_t)p.y * 4 + 3);
    edge(yv, q0, q1, q2, q3);
  }
  agg[(size_t)n * CH + 2 * lane]     = acc0;
  agg[(size_t)n * CH + 2 * lane + 1] = acc1;
}

// ---------------------------------------------------------------- update, tiled:
// raw may alias agg: each wave stages its own agg rows before storing, rows wave-exclusive.
__global__ __launch_bounds__(256) void upd_tiled(const void* __restrict__ x, int x_sel,
                                                 const float* __restrict__ agg,
                                                 const int* __restrict__ cnt,
                                                 const void* __restrict__ W,
                                                 const void* __restrict__ bupd,
                                                 const int* __restrict__ flags,
                                                 float* __restrict__ raw) {
  __shared__ float xs[4][NPW][KUPD];  // 32 KB
  const int wave = threadIdx.x >> 6;
  const int lane = threadIdx.x & 63;
  const int n0 = (blockIdx.x * 4 + wave) * NPW;
  const int xf = resolve_f32(x_sel, flags), wf = flags[3];

#pragma unroll
  for (int r = 0; r < NPW; ++r) {
    int n = n0 + r;
    float2 a = ld2(x, xf, (size_t)n * 64 + lane);
    xs[wave][r][2 * lane]     = a.x;
    xs[wave][r][2 * lane + 1] = a.y;
    int c = cnt[n];
    float inv = 1.f / (float)(c > 1 ? c : 1);
    xs[wave][r][CH + 2 * lane]     = agg[(size_t)n * CH + 2 * lane] * inv;
    xs[wave][r][CH + 2 * lane + 1] = agg[(size_t)n * CH + 2 * lane + 1] * inv;
  }
  __syncthreads();

  float acc0[NPW], acc1[NPW];
#pragma unroll
  for (int r = 0; r < NPW; ++r) { acc0[r] = 0.f; acc1[r] = 0.f; }

#pragma unroll 4
  for (int k = 0; k < KUPD; k += 2) {
    float2 w0 = ld2(W, wf, (size_t)k * 64 + lane);
    float2 w1 = ld2(W, wf, (size_t)(k + 1) * 64 + lane);
#pragma unroll
    for (int r = 0; r < NPW; ++r) {
      float2 a = *(const float2*)&xs[wave][r][k];
      acc0[r] += a.x * w0.x;
      acc1[r] += a.x * w0.y;
      acc0[r] += a.y * w1.x;
      acc1[r] += a.y * w1.y;
    }
  }

  float2 b = ld2(bupd, wf, lane);
#pragma unroll
  for (int r = 0; r < NPW; ++r) {
    size_t n = (size_t)(n0 + r);
    raw[n * CH + 2 * lane]     = acc0[r] + b.x;
    raw[n * CH + 2 * lane + 1] = acc1[r] + b.y;
  }
}

// ---------------------------------------------------------------- row L2-normalize + bias (+optional ReLU) -> f32
__global__ __launch_bounds__(256) void norm_simple(const float* __restrict__ raw,
                                                   const void* __restrict__ bias,
                                                   const int* __restrict__ flags,
                                                   float* __restrict__ out,
                                                   int relu) {
  int row = blockIdx.x * 4 + (threadIdx.x >> 6);
  int lane = threadIdx.x & 63;
  const int wf = flags[3];
  float v0 = raw[(size_t)row * CH + 2 * lane];
  float v1 = raw[(size_t)row * CH + 2 * lane + 1];
  float ss = v0 * v0 + v1 * v1;
#pragma unroll
  for (int o = 32; o; o >>= 1) ss += __shfl_xor(ss, o);
  float inv = 1.0f / fmaxf(sqrtf(ss), 1e-12f);
  float2 b = ld2(bias, wf, lane);
  float o0 = v0 * inv + b.x;
  float o1 = v1 * inv + b.y;
  if (relu) {
    o0 = fmaxf(o0, 0.0f);
    o1 = fmaxf(o1, 0.0f);
  }
  out[(size_t)row * CH + 2 * lane] = o0;
  out[(size_t)row * CH + 2 * lane + 1] = o1;
}

// ---------------------------------------------------------------- host
extern "C" void kernel_launch(void* const* d_in, const int* in_sizes, int n_in,
                              void* d_out, int out_size, void* d_ws, size_t ws_size,
                              hipStream_t stream) {
  const void* x   = d_in[0];
  const int*  ei  = (const int*)d_in[1];
  const void* ea  = d_in[2];
  const void* wm1 = d_in[3];
  const void* bm1 = d_in[4];
  const void* wu1 = d_in[5];
  const void* bu1 = d_in[6];
  const void* bi1 = d_in[7];
  const void* wm2 = d_in[8];
  const void* bm2 = d_in[9];
  const void* wu2 = d_in[10];
  const void* bu2 = d_in[11];
  const void* bi2 = d_in[12];
  float* out = (float*)d_out;

  // Workspace (~117 MB): flags | cnt | fill | rowptr | sev (CSR {src,eid}) | A=agg/raw | B=y.
  char* base = (char*)d_ws;
  size_t off = 0;
  auto alloc = [&](size_t b) { size_t o = off; off += (b + 255) & ~(size_t)255; return o; };
  size_t flags_o = alloc(16);
  size_t cnt_o   = alloc((size_t)N_NODES * 4);
  size_t fill_o  = alloc((size_t)N_NODES * 4);
  size_t zero_end = off;                       // memset covers flags|cnt|fill only
  size_t rowp_o  = alloc((size_t)(N_NODES + 1) * 4);
  size_t sev_o   = alloc((size_t)N_EDGES * 8);
  size_t agg_o   = alloc((size_t)N_NODES * CH * 4);
  size_t y_o     = alloc((size_t)N_NODES * CH * 4);
  (void)ws_size; (void)n_in; (void)in_sizes; (void)out_size;

  int*    flags = (int*)(base + flags_o);
  int*    cntp  = (int*)(base + cnt_o);
  int*    fillp = (int*)(base + fill_o);
  int*    rowp  = (int*)(base + rowp_o);
  int2*   sevp  = (int2*)(base + sev_o);
  float*  aggp  = (float*)(base + agg_o);
  float*  rawp  = aggp;                 // alias (see upd_tiled note)
  float2* yp    = (float2*)(base + y_o);
  float*  hp    = out;                  // layer-1 output (f32) lives in d_out

  hipMemsetAsync(base, 0, zero_end, stream);
  detect_kernel<<<1, 256, 0, stream>>>(ei, (const ushort*)x, (const ushort*)ea,
                                       (const ushort*)wm1, flags);
  count_kernel<<<(N_EDGES + 255) / 256, 256, 0, stream>>>(ei, flags, cntp);
  scan_kernel<<<1, 1024, 0, stream>>>(cntp, rowp);
  scatter_kernel<<<(N_EDGES + 255) / 256, 256, 0, stream>>>(ei, flags, rowp, fillp, sevp);

  const int ggrid = N_NODES / (4 * NPW);  // 3125
  const int agrid = N_NODES / 4;          // 25000 (one wave per node)

  // ---- layer 1
  gemm_node<<<ggrid, 256, 0, stream>>>(x, 1, wm1, bm1, flags, (float*)yp);
  agg_csr<<<agrid, 256, 0, stream>>>(yp, ea, wm1, rowp, sevp, flags, aggp);
  upd_tiled<<<ggrid, 256, 0, stream>>>(x, 1, aggp, cntp, wu1, bu1, flags, rawp);
  norm_simple<<<N_NODES / 4, 256, 0, stream>>>(rawp, bi1, flags, hp, 1);

  // ---- layer 2 (h is f32 in d_out -> x_sel=2 forces f32)
  gemm_node<<<ggrid, 256, 0, stream>>>(hp, 2, wm2, bm2, flags, (float*)yp);
  agg_csr<<<agrid, 256, 0, stream>>>(yp, ea, wm2, rowp, sevp, flags, aggp);
  upd_tiled<<<ggrid, 256, 0, stream>>>(hp, 2, aggp, cntp, wu2, bu2, flags, rawp);
  norm_simple<<<N_NODES / 4, 256, 0, stream>>>(rawp, bi2, flags, out, 0);
}

// Round 4
// 1409.757 us; speedup vs baseline: 15.8769x; 1.2931x over previous
//
#include <hip/hip_runtime.h>
#include <stdint.h>

#define N_NODES 100000
#define N_EDGES 1600000
#define CH 128
#define EDGE_DIM 16
#define KUPD (2 * CH)         // 256
#define NPW 8                 // nodes per wave (gemm/upd)

__device__ __forceinline__ float bf2f(ushort u) {
  union { uint i; float f; } c; c.i = ((uint)u) << 16; return c.f;
}
__device__ __forceinline__ ushort f2bf(float f) {
  union { float f; uint i; } c; c.f = f;
  return (ushort)((c.i + 0x7FFFu + ((c.i >> 16) & 1u)) >> 16);
}
// dtype-dispatched paired load: elements (2*pi, 2*pi+1)
__device__ __forceinline__ float2 ld2(const void* p, int f32, size_t pi) {
  if (f32) return ((const float2*)p)[pi];
  uint u = ((const uint*)p)[pi];
  return make_float2(bf2f((ushort)(u & 0xFFFF)), bf2f((ushort)(u >> 16)));
}
// dtype-dispatched quad load: elements (4*qi .. 4*qi+3)
__device__ __forceinline__ float4 ld4(const void* p, int f32, size_t qi) {
  if (f32) return ((const float4*)p)[qi];
  uint2 u = ((const uint2*)p)[qi];
  float4 r;
  r.x = bf2f((ushort)(u.x & 0xFFFF)); r.y = bf2f((ushort)(u.x >> 16));
  r.z = bf2f((ushort)(u.y & 0xFFFF)); r.w = bf2f((ushort)(u.y >> 16));
  return r;
}
// x_sel: 0 = force bf16, 1 = use detected x flag, 2 = force f32
__device__ __forceinline__ int resolve_f32(int x_sel, const int* flags) {
  return (x_sel == 2) ? 1 : (x_sel == 1 ? flags[1] : 0);
}

// ---------------------------------------------------------------- runtime layout/dtype detection
// flags[0]=1 -> edge_index int32 [2,E]. flags[1..3]=1 -> x / edge_attr / weights are f32.
__global__ __launch_bounds__(256) void detect_kernel(const int* __restrict__ ei,
                                                     const ushort* __restrict__ xu,
                                                     const ushort* __restrict__ eau,
                                                     const ushort* __restrict__ wu,
                                                     int* __restrict__ flags) {
  int any = 0, fx = 0, fe = 0, fw = 0;
  for (int i = threadIdx.x; i < 4096; i += 256) any |= ei[2 * i + 1];
  for (int i = threadIdx.x; i < 16384; i += 256) {
    fx |= (((xu[2 * i] >> 7) & 0xFF) == 0xFF);
    fe |= (((eau[2 * i] >> 7) & 0xFF) == 0xFF);
  }
  for (int i = threadIdx.x; i < 8192; i += 256) {
    fw |= (((wu[2 * i] >> 7) & 0xFF) == 0xFF);
  }
  if (any) atomicOr(flags + 0, 1);
  if (fx)  atomicOr(flags + 1, 1);
  if (fe)  atomicOr(flags + 2, 1);
  if (fw)  atomicOr(flags + 3, 1);
}

__device__ __forceinline__ void load_edge(const int* __restrict__ ei, int i32, int e,
                                          int& s, int& d) {
  if (i32) { s = ei[e]; d = ei[N_EDGES + e]; }
  else     { s = ei[2 * e]; d = ei[2 * N_EDGES + 2 * e]; }
  s = min(max(s, 0), N_NODES - 1);
  d = min(max(d, 0), N_NODES - 1);
}

// ---------------------------------------------------------------- degree count
__global__ __launch_bounds__(256) void count_kernel(const int* __restrict__ ei,
                                                    const int* __restrict__ flags,
                                                    int* __restrict__ cnt) {
  int e = blockIdx.x * 256 + threadIdx.x;
  if (e >= N_EDGES) return;
  int s, d;
  load_edge(ei, flags[0], e, s, d);
  atomicAdd(&cnt[d], 1);
}

// ---------------------------------------------------------------- exclusive prefix scan of cnt -> rowptr
__global__ __launch_bounds__(1024) void scan_kernel(const int* __restrict__ cnt,
                                                    int* __restrict__ rowptr) {
  __shared__ int part[1024];
  const int t = threadIdx.x;
  const int CHUNK = (N_NODES + 1023) / 1024;  // 98
  int base = t * CHUNK;
  int lim = min(base + CHUNK, N_NODES);
  int s = 0;
  for (int i = base; i < lim; ++i) s += cnt[i];
  part[t] = s;
  __syncthreads();
  for (int off = 1; off < 1024; off <<= 1) {
    int v = (t >= off) ? part[t - off] : 0;
    __syncthreads();
    part[t] += v;
    __syncthreads();
  }
  int excl = (t == 0) ? 0 : part[t - 1];
  for (int i = base; i < lim; ++i) { rowptr[i] = excl; excl += cnt[i]; }
  if (t == 1023) rowptr[N_NODES] = part[1023];
}

// ---------------------------------------------------------------- CSR scatter: {src, eid} sorted by dst
__global__ __launch_bounds__(256) void scatter_kernel(const int* __restrict__ ei,
                                                      const int* __restrict__ flags,
                                                      const int* __restrict__ rowptr,
                                                      int* __restrict__ fill,
                                                      int2* __restrict__ sev) {
  int e = blockIdx.x * 256 + threadIdx.x;
  if (e >= N_EDGES) return;
  int s, d;
  load_edge(ei, flags[0], e, s, d);
  int pos = atomicAdd(&fill[d], 1);
  sev[rowptr[d] + pos] = make_int2(s, e);
}

// ---------------------------------------------------------------- node-level GEMM: y = x @ W[0:128] + b
// Output PACKED BF16 pairs (uint per lane): halves the agg gather bytes (R3's
// throughput wall). Rounding hits only the gathered message operand; all
// accumulation stays f32.
__global__ __launch_bounds__(256) void gemm_node(const void* __restrict__ x, int x_sel,
                                                 const void* __restrict__ W,
                                                 const void* __restrict__ b,
                                                 const int* __restrict__ flags,
                                                 uint* __restrict__ ybf) {
  __shared__ float xs[4][NPW][CH];  // 16 KB
  const int wave = threadIdx.x >> 6;
  const int lane = threadIdx.x & 63;
  const int n0 = (blockIdx.x * 4 + wave) * NPW;  // N = 32*gridDim exactly
  const int xf = resolve_f32(x_sel, flags), wf = flags[3];

#pragma unroll
  for (int r = 0; r < NPW; ++r) {
    float2 a = ld2(x, xf, (size_t)(n0 + r) * 64 + lane);
    xs[wave][r][2 * lane]     = a.x;
    xs[wave][r][2 * lane + 1] = a.y;
  }
  __syncthreads();

  float acc0[NPW], acc1[NPW];
#pragma unroll
  for (int r = 0; r < NPW; ++r) { acc0[r] = 0.f; acc1[r] = 0.f; }

#pragma unroll 4
  for (int k = 0; k < CH; k += 2) {
    float2 w0 = ld2(W, wf, (size_t)k * 64 + lane);
    float2 w1 = ld2(W, wf, (size_t)(k + 1) * 64 + lane);
#pragma unroll
    for (int r = 0; r < NPW; ++r) {
      float2 a = *(const float2*)&xs[wave][r][k];
      acc0[r] += a.x * w0.x;
      acc1[r] += a.x * w0.y;
      acc0[r] += a.y * w1.x;
      acc1[r] += a.y * w1.y;
    }
  }

  float2 bb = ld2(b, wf, lane);
#pragma unroll
  for (int r = 0; r < NPW; ++r) {
    size_t n = (size_t)(n0 + r);
    uint pk = (uint)f2bf(acc0[r] + bb.x) | ((uint)f2bf(acc1[r] + bb.y) << 16);
    ybf[n * 64 + lane] = pk;
  }
}

// ---------------------------------------------------------------- CSR aggregation:
// One wave per dst node, 4-edge batches. All wave-uniform data (sev pairs, ea
// rows) is readfirstlane'd onto the SCALAR path (s_load), so the VMEM stream is
// just 4x 4-byte y-gathers per batch (bf16-packed rows, 256B/row: half R3's
// gather bytes & lines). W_e slice lives in 32 VGPRs. f32 accumulate, CSR order.
__global__ __launch_bounds__(256, 4) void agg_csr(const uint* __restrict__ ybf,
                                                  const void* __restrict__ ea,
                                                  const void* __restrict__ W,
                                                  const int* __restrict__ rowptr,
                                                  const int2* __restrict__ sev,
                                                  const int* __restrict__ flags,
                                                  float* __restrict__ agg) {
  const int wave = threadIdx.x >> 6;
  const int lane = threadIdx.x & 63;
  const int ef = flags[2], wf = flags[3];

  float wex[EDGE_DIM], wey[EDGE_DIM];
#pragma unroll
  for (int k = 0; k < EDGE_DIM; ++k) {
    float2 wv = ld2(W, wf, (size_t)(CH + k) * 64 + lane);
    wex[k] = wv.x; wey[k] = wv.y;
  }

  const int n = blockIdx.x * 4 + wave;  // grid = N/4 exactly
  const int beg = rowptr[n], end = rowptr[n + 1];
  float acc0 = 0.f, acc1 = 0.f;

  auto edge = [&](uint yu, float4 q0, float4 q1, float4 q2, float4 q3) {
    float av[16] = {q0.x, q0.y, q0.z, q0.w, q1.x, q1.y, q1.z, q1.w,
                    q2.x, q2.y, q2.z, q2.w, q3.x, q3.y, q3.z, q3.w};
    float z0 = 0.f, z1 = 0.f;
#pragma unroll
    for (int k = 0; k < EDGE_DIM; ++k) {
      z0 += av[k] * wex[k];
      z1 += av[k] * wey[k];
    }
    acc0 += fmaxf(bf2f((ushort)(yu & 0xFFFF)) + z0, 0.f);
    acc1 += fmaxf(bf2f((ushort)(yu >> 16)) + z1, 0.f);
  };

  int j = beg;
  for (; j + 4 <= end; j += 4) {
    int2 p0 = sev[j], p1 = sev[j + 1], p2 = sev[j + 2], p3 = sev[j + 3];
    int s0 = __builtin_amdgcn_readfirstlane(p0.x), e0 = __builtin_amdgcn_readfirstlane(p0.y);
    int s1 = __builtin_amdgcn_readfirstlane(p1.x), e1 = __builtin_amdgcn_readfirstlane(p1.y);
    int s2 = __builtin_amdgcn_readfirstlane(p2.x), e2 = __builtin_amdgcn_readfirstlane(p2.y);
    int s3 = __builtin_amdgcn_readfirstlane(p3.x), e3 = __builtin_amdgcn_readfirstlane(p3.y);
    uint y0 = ybf[(size_t)s0 * 64 + lane];
    uint y1 = ybf[(size_t)s1 * 64 + lane];
    uint y2 = ybf[(size_t)s2 * 64 + lane];
    uint y3 = ybf[(size_t)s3 * 64 + lane];
    float4 a00 = ld4(ea, ef, (size_t)e0 * 4 + 0);
    float4 a01 = ld4(ea, ef, (size_t)e0 * 4 + 1);
    float4 a02 = ld4(ea, ef, (size_t)e0 * 4 + 2);
    float4 a03 = ld4(ea, ef, (size_t)e0 * 4 + 3);
    float4 a10 = ld4(ea, ef, (size_t)e1 * 4 + 0);
    float4 a11 = ld4(ea, ef, (size_t)e1 * 4 + 1);
    float4 a12 = ld4(ea, ef, (size_t)e1 * 4 + 2);
    float4 a13 = ld4(ea, ef, (size_t)e1 * 4 + 3);
    float4 a20 = ld4(ea, ef, (size_t)e2 * 4 + 0);
    float4 a21 = ld4(ea, ef, (size_t)e2 * 4 + 1);
    float4 a22 = ld4(ea, ef, (size_t)e2 * 4 + 2);
    float4 a23 = ld4(ea, ef, (size_t)e2 * 4 + 3);
    float4 a30 = ld4(ea, ef, (size_t)e3 * 4 + 0);
    float4 a31 = ld4(ea, ef, (size_t)e3 * 4 + 1);
    float4 a32 = ld4(ea, ef, (size_t)e3 * 4 + 2);
    float4 a33 = ld4(ea, ef, (size_t)e3 * 4 + 3);
    edge(y0, a00, a01, a02, a03);
    edge(y1, a10, a11, a12, a13);
    edge(y2, a20, a21, a22, a23);
    edge(y3, a30, a31, a32, a33);
  }
  for (; j < end; ++j) {  // tail (wave-uniform trip count)
    int2 p = sev[j];
    int s = __builtin_amdgcn_readfirstlane(p.x), e = __builtin_amdgcn_readfirstlane(p.y);
    uint yu = ybf[(size_t)s * 64 + lane];
    float4 q0 = ld4(ea, ef, (size_t)e * 4 + 0);
    float4 q1 = ld4(ea, ef, (size_t)e * 4 + 1);
    float4 q2 = ld4(ea, ef, (size_t)e * 4 + 2);
    float4 q3 = ld4(ea, ef, (size_t)e * 4 + 3);
    edge(yu, q0, q1, q2, q3);
  }
  agg[(size_t)n * CH + 2 * lane]     = acc0;
  agg[(size_t)n * CH + 2 * lane + 1] = acc1;
}

// ---------------------------------------------------------------- update + L2-normalize + bias fused:
// GEMM part as before; then the wave holds the full output row (2 cols x 64
// lanes), so the row norm is a 6-step shfl reduce per row. Writes the layer
// output DIRECTLY (raw buffer + norm kernel eliminated). Degree comes from
// rowptr (cnt buffer not needed here). Layer 2 writes d_out while reading its
// own rows of h (=d_out): each block stages its rows in LDS before any store,
// and blocks own disjoint rows.
__global__ __launch_bounds__(256) void upd_fused(const void* __restrict__ x, int x_sel,
                                                 const float* __restrict__ agg,
                                                 const int* __restrict__ rowptr,
                                                 const void* __restrict__ W,
                                                 const void* __restrict__ bupd,
                                                 const void* __restrict__ bias,
                                                 const int* __restrict__ flags,
                                                 float* __restrict__ out,
                                                 int relu) {
  __shared__ float xs[4][NPW][KUPD];  // 32 KB
  const int wave = threadIdx.x >> 6;
  const int lane = threadIdx.x & 63;
  const int n0 = (blockIdx.x * 4 + wave) * NPW;
  const int xf = resolve_f32(x_sel, flags), wf = flags[3];

#pragma unroll
  for (int r = 0; r < NPW; ++r) {
    int n = n0 + r;
    float2 a = ld2(x, xf, (size_t)n * 64 + lane);
    xs[wave][r][2 * lane]     = a.x;
    xs[wave][r][2 * lane + 1] = a.y;
    int c = rowptr[n + 1] - rowptr[n];
    float inv = 1.f / (float)(c > 1 ? c : 1);
    xs[wave][r][CH + 2 * lane]     = agg[(size_t)n * CH + 2 * lane] * inv;
    xs[wave][r][CH + 2 * lane + 1] = agg[(size_t)n * CH + 2 * lane + 1] * inv;
  }
  __syncthreads();

  float acc0[NPW], acc1[NPW];
#pragma unroll
  for (int r = 0; r < NPW; ++r) { acc0[r] = 0.f; acc1[r] = 0.f; }

#pragma unroll 4
  for (int k = 0; k < KUPD; k += 2) {
    float2 w0 = ld2(W, wf, (size_t)k * 64 + lane);
    float2 w1 = ld2(W, wf, (size_t)(k + 1) * 64 + lane);
#pragma unroll
    for (int r = 0; r < NPW; ++r) {
      float2 a = *(const float2*)&xs[wave][r][k];
      acc0[r] += a.x * w0.x;
      acc1[r] += a.x * w0.y;
      acc0[r] += a.y * w1.x;
      acc1[r] += a.y * w1.y;
    }
  }

  float2 b  = ld2(bupd, wf, lane);
  float2 bi = ld2(bias, wf, lane);
#pragma unroll
  for (int r = 0; r < NPW; ++r) {
    float r0 = acc0[r] + b.x;
    float r1 = acc1[r] + b.y;
    float ss = r0 * r0 + r1 * r1;
#pragma unroll
    for (int o = 32; o; o >>= 1) ss += __shfl_xor(ss, o);
    float innv = 1.0f / fmaxf(sqrtf(ss), 1e-12f);
    float o0 = r0 * innv + bi.x;
    float o1 = r1 * innv + bi.y;
    if (relu) {
      o0 = fmaxf(o0, 0.0f);
      o1 = fmaxf(o1, 0.0f);
    }
    size_t n = (size_t)(n0 + r);
    out[n * CH + 2 * lane]     = o0;
    out[n * CH + 2 * lane + 1] = o1;
  }
}

// ---------------------------------------------------------------- host
extern "C" void kernel_launch(void* const* d_in, const int* in_sizes, int n_in,
                              void* d_out, int out_size, void* d_ws, size_t ws_size,
                              hipStream_t stream) {
  const void* x   = d_in[0];
  const int*  ei  = (const int*)d_in[1];
  const void* ea  = d_in[2];
  const void* wm1 = d_in[3];
  const void* bm1 = d_in[4];
  const void* wu1 = d_in[5];
  const void* bu1 = d_in[6];
  const void* bi1 = d_in[7];
  const void* wm2 = d_in[8];
  const void* bm2 = d_in[9];
  const void* wu2 = d_in[10];
  const void* bu2 = d_in[11];
  const void* bi2 = d_in[12];
  float* out = (float*)d_out;

  // Workspace (~92 MB): flags | cnt | fill | rowptr | sev (CSR {src,eid}) | agg | ybf (bf16).
  char* base = (char*)d_ws;
  size_t off = 0;
  auto alloc = [&](size_t b) { size_t o = off; off += (b + 255) & ~(size_t)255; return o; };
  size_t flags_o = alloc(16);
  size_t cnt_o   = alloc((size_t)N_NODES * 4);
  size_t fill_o  = alloc((size_t)N_NODES * 4);
  size_t zero_end = off;                       // memset covers flags|cnt|fill only
  size_t rowp_o  = alloc((size_t)(N_NODES + 1) * 4);
  size_t sev_o   = alloc((size_t)N_EDGES * 8);
  size_t agg_o   = alloc((size_t)N_NODES * CH * 4);
  size_t y_o     = alloc((size_t)N_NODES * CH * 2);   // packed bf16
  (void)ws_size; (void)n_in; (void)in_sizes; (void)out_size;

  int*    flags = (int*)(base + flags_o);
  int*    cntp  = (int*)(base + cnt_o);
  int*    fillp = (int*)(base + fill_o);
  int*    rowp  = (int*)(base + rowp_o);
  int2*   sevp  = (int2*)(base + sev_o);
  float*  aggp  = (float*)(base + agg_o);
  uint*   ybfp  = (uint*)(base + y_o);
  float*  hp    = out;                  // layer-1 output (f32) lives in d_out

  hipMemsetAsync(base, 0, zero_end, stream);
  detect_kernel<<<1, 256, 0, stream>>>(ei, (const ushort*)x, (const ushort*)ea,
                                       (const ushort*)wm1, flags);
  count_kernel<<<(N_EDGES + 255) / 256, 256, 0, stream>>>(ei, flags, cntp);
  scan_kernel<<<1, 1024, 0, stream>>>(cntp, rowp);
  scatter_kernel<<<(N_EDGES + 255) / 256, 256, 0, stream>>>(ei, flags, rowp, fillp, sevp);

  const int ggrid = N_NODES / (4 * NPW);  // 3125
  const int agrid = N_NODES / 4;          // 25000 (one wave per node)

  // ---- layer 1
  gemm_node<<<ggrid, 256, 0, stream>>>(x, 1, wm1, bm1, flags, ybfp);
  agg_csr<<<agrid, 256, 0, stream>>>(ybfp, ea, wm1, rowp, sevp, flags, aggp);
  upd_fused<<<ggrid, 256, 0, stream>>>(x, 1, aggp, rowp, wu1, bu1, bi1, flags, hp, 1);

  // ---- layer 2 (h is f32 in d_out -> x_sel=2 forces f32)
  gemm_node<<<ggrid, 256, 0, stream>>>(hp, 2, wm2, bm2, flags, ybfp);
  agg_csr<<<agrid, 256, 0, stream>>>(ybfp, ea, wm2, rowp, sevp, flags, aggp);
  upd_fused<<<ggrid, 256, 0, stream>>>(hp, 2, aggp, rowp, wu2, bu2, bi2, flags, out, 0);
}